// Round 10
// baseline (1694.802 us; speedup 1.0000x reference)
//
#include <hip/hip_runtime.h>

#define NB 16
#define NPTS 4096
#define NS 1024
#define NK 32
#define NCF 64

// All I/O is float32. Zero workspace bytes used. kNN parks its 32 indices
// (bit-cast to float) in the first 128B of each query's 512B output row;
// mlp_kernel reads them back and fully overwrites the row. Row ORDER of the
// 32 neighbors is irrelevant (max-pool) — only the index SET must be exact.
//
// REGISTER DISCIPLINE (r7-r10 lessons):
//  - __launch_bounds__ only CAPS VGPRs; the compiler may still rematerialize
//    arrays from LDS. Keep per-lane arrays small enough to fit the default
//    cap (fps: 8pts=32 regs @512thr -> VGPR 40, no remat, 2 waves/SIMD).
//  - knn needs (256,4): 128-VGPR budget for kD[32]+kI[32] in registers.

#define F_INF __int_as_float(0x7f800000)

#define DPP_SHR1   0x111
#define DPP_SHR2   0x112
#define DPP_SHR4   0x114
#define DPP_SHR8   0x118
#define DPP_BCAST15 0x142
#define DPP_BCAST31 0x143

// one max step of a wave64 u64-key reduction via DPP (invalid lanes keep self)
#define DPP_MAX_STEP(cur, CTRL) do{ \
  int lo_=__builtin_amdgcn_update_dpp((int)(unsigned)(cur),(int)(unsigned)(cur),CTRL,0xF,0xF,false); \
  int hi_=__builtin_amdgcn_update_dpp((int)(unsigned)((cur)>>32),(int)(unsigned)((cur)>>32),CTRL,0xF,0xF,false); \
  unsigned long long nk_=(((unsigned long long)(unsigned)hi_)<<32)|(unsigned)lo_; \
  if (nk_>(cur)) (cur)=nk_; \
}while(0)

// ---------------- FPS: 1 block/batch, 512 thr, DPP argmax ----------------
// key = (dist_bits<<32) | (4095-idx): u64 max == max dist, first index.
// 8 pts/lane: all arrays in registers at VGPR~40 (r7-measured), 2 waves/SIMD.
__global__ __launch_bounds__(512) void fps_kernel(
  const float* __restrict__ xyz, float* __restrict__ out)
{
  __shared__ float sxyz[NPTS*3];
  __shared__ unsigned long long skey[2][8];
  __shared__ int sfps[NS];
  const int b = blockIdx.x, tid = threadIdx.x;

  { // stage xyz -> LDS
    const float4* src=(const float4*)(xyz+(size_t)b*NPTS*3);
    float4* dst=(float4*)sxyz;
    for (int i=tid;i<NPTS*3/4;i+=512) dst[i]=src[i];
  }
  __syncthreads();
  // 8 points per thread in registers (ascending index with tid)
  float px[8],py[8],pz[8],dist[8];
  #pragma unroll
  for (int r=0;r<8;r++){
    int p=tid*8+r;
    px[r]=sxyz[p*3]; py[r]=sxyz[p*3+1]; pz[r]=sxyz[p*3+2];
    dist[r]=1e10f;
  }
  int far=0;
  for (int s=0;s<NS;++s){
    float cx=sxyz[far*3],cy=sxyz[far*3+1],cz=sxyz[far*3+2];
    float bv=-1.0f; int bslot=0;
    #pragma unroll
    for (int r=0;r<8;r++){
      float dx=__fsub_rn(px[r],cx);
      float dy=__fsub_rn(py[r],cy);
      float dz=__fsub_rn(pz[r],cz);
      float d2=__fadd_rn(__fadd_rn(__fmul_rn(dx,dx),__fmul_rn(dy,dy)),__fmul_rn(dz,dz));
      float nd=fminf(dist[r],d2);
      dist[r]=nd;
      if (nd>bv){bv=nd;bslot=r;}      // strict > keeps first index in lane
    }
    int bidx=tid*8+bslot;
    unsigned long long cur=(((unsigned long long)__float_as_uint(bv))<<32)
                           |(unsigned)(4095-bidx);
    DPP_MAX_STEP(cur,DPP_SHR1);
    DPP_MAX_STEP(cur,DPP_SHR2);
    DPP_MAX_STEP(cur,DPP_SHR4);
    DPP_MAX_STEP(cur,DPP_SHR8);
    DPP_MAX_STEP(cur,DPP_BCAST15);
    DPP_MAX_STEP(cur,DPP_BCAST31);
    const int par=s&1;
    if ((tid&63)==63) skey[par][tid>>6]=cur;
    __syncthreads();
    unsigned long long m=skey[par][0];
    #pragma unroll
    for (int w=1;w<8;w++){ unsigned long long o=skey[par][w]; if (o>m) m=o; }
    far=4095-(int)(m&0xFFFFFFFFu);
    if (tid==0) sfps[s]=far;
  }
  __syncthreads();
  for (int s=tid;s<NS;s+=512){
    int p=sfps[s];
    size_t o=((size_t)b*NS+s)*3;
    out[o]=sxyz[p*3]; out[o+1]=sxyz[p*3+1]; out[o+2]=sxyz[p*3+2];
  }
}

// ---------------- kNN: 256 thr (4 waves), 16 queries/block ----------------
// 16 lanes/query scan interleaved 256-pt partitions from GLOBAL (L1
// broadcast). Per-lane sorted top-32 via med3 insert; lists in REGISTERS
// thanks to (256,4)'s 128-VGPR budget.
__global__ __launch_bounds__(256, 4) void knn_kernel(
  const float* __restrict__ xyz, const float* __restrict__ newxyz,
  float* __restrict__ out2)
{
  __shared__ unsigned long long sdump[64*33];  // 16.9 KB (one wave's lists)
  __shared__ unsigned long long sl1[16*33];    // 4.2 KB (level-1 outputs)
  const int tid=threadIdx.x;
  const int wave=tid>>6, lane=tid&63;
  const int qw=lane>>4;               // query-within-wave 0..3
  const int part=lane&15;             // partition 0..15
  const int gq=blockIdx.x*16+wave*4+qw;
  const int b=gq>>10;
  const float* base=xyz+(size_t)b*NPTS*3;

  float ax=newxyz[(size_t)gq*3],ay=newxyz[(size_t)gq*3+1],az=newxyz[(size_t)gq*3+2];
  float a2=__fadd_rn(__fadd_rn(__fmul_rn(ax,ax),__fmul_rn(ay,ay)),__fmul_rn(az,az));
  float kD[NK]; int kI[NK];
  #pragma unroll
  for (int p=0;p<NK;p++){kD[p]=F_INF;kI[p]=0x7FFFFFFF;}
  #pragma unroll 2
  for (int t=0;t<NPTS/16;++t){
    int n=(t<<4)|part;
    float bx=base[n*3],by=base[n*3+1],bz=base[n*3+2];
    float b2=__fadd_rn(__fadd_rn(__fmul_rn(bx,bx),__fmul_rn(by,by)),__fmul_rn(bz,bz));
    float ab=__fadd_rn(__fadd_rn(__fmul_rn(ax,bx),__fmul_rn(ay,by)),__fmul_rn(az,bz));
    float tt=__fadd_rn(__fsub_rn(a2,__fmul_rn(2.0f,ab)),b2);
    float d2=fmaxf(tt,0.0f);
    if (d2<kD[NK-1]){                  // strict <: in-lane (d2,idx) stability
      #pragma unroll
      for (int p=NK-1;p>0;--p){
        bool cm1=d2<kD[p-1];
        bool cp=d2<kD[p];
        kI[p]=cm1?kI[p-1]:(cp?n:kI[p]);
        kD[p]=__builtin_fminf(__builtin_fmaxf(kD[p-1],d2),kD[p]); // med3(sorted)
      }
      if (d2<kD[0]){kD[0]=d2;kI[0]=n;}
    }
  }
  // ---- 4-phase merge
  #pragma unroll 1
  for (int ph=0;ph<4;++ph){
    if (wave==ph){
      unsigned long long* row=sdump+(size_t)lane*33;
      #pragma unroll
      for (int p=0;p<NK;p++)
        row[p]=(((unsigned long long)__float_as_uint(kD[p]))<<32)|(unsigned)kI[p];
    }
    __syncthreads();
    if (tid<16){                        // level 1: query qq, group g
      int qq=tid>>2, g=tid&3;
      const unsigned long long* r0=sdump+(size_t)(qq*16+g*4+0)*33;
      const unsigned long long* r1=sdump+(size_t)(qq*16+g*4+1)*33;
      const unsigned long long* r2=sdump+(size_t)(qq*16+g*4+2)*33;
      const unsigned long long* r3=sdump+(size_t)(qq*16+g*4+3)*33;
      unsigned long long* o=sl1+(size_t)tid*33;
      int h0=0,h1=0,h2=0,h3=0;
      unsigned long long c0=r0[0],c1=r1[0],c2=r2[0],c3=r3[0];
      for (int i=0;i<NK;++i){
        bool s01=c1<c0; unsigned long long m01=s01?c1:c0;
        bool s23=c3<c2; unsigned long long m23=s23?c3:c2;
        bool sm=m23<m01; unsigned long long m=sm?m23:m01;
        o[i]=m;
        int w=sm?(s23?3:2):(s01?1:0);
        if (w==0){h0++; c0=(h0<NK)?r0[h0]:~0ull;}
        else if (w==1){h1++; c1=(h1<NK)?r1[h1]:~0ull;}
        else if (w==2){h2++; c2=(h2<NK)?r2[h2]:~0ull;}
        else {h3++; c3=(h3<NK)?r3[h3]:~0ull;}
      }
    }
    __syncthreads();
    if (tid<4){                         // level 2 -> output indices
      const unsigned long long* r0=sl1+(size_t)(tid*4+0)*33;
      const unsigned long long* r1=sl1+(size_t)(tid*4+1)*33;
      const unsigned long long* r2=sl1+(size_t)(tid*4+2)*33;
      const unsigned long long* r3=sl1+(size_t)(tid*4+3)*33;
      float* orow=out2+(size_t)(blockIdx.x*16+ph*4+tid)*128;
      int h0=0,h1=0,h2=0,h3=0;
      unsigned long long c0=r0[0],c1=r1[0],c2=r2[0],c3=r3[0];
      for (int i=0;i<NK;++i){
        bool s01=c1<c0; unsigned long long m01=s01?c1:c0;
        bool s23=c3<c2; unsigned long long m23=s23?c3:c2;
        bool sm=m23<m01; unsigned long long m=sm?m23:m01;
        orow[i]=__int_as_float((int)(unsigned)(m&0xFFFFFFFFu));
        int w=sm?(s23?3:2):(s01?1:0);
        if (w==0){h0++; c0=(h0<NK)?r0[h0]:~0ull;}
        else if (w==1){h1++; c1=(h1<NK)?r1[h1]:~0ull;}
        else if (w==2){h2++; c2=(h2<NK)?r2[h2]:~0ull;}
        else {h3++; c3=(h3<NK)?r3[h3]:~0ull;}
      }
    }
    __syncthreads();
  }
}

// ---------------- fused group + MLP(3) + maxpool --------------------------
// 128 threads = 4 queries x 32 neighbor rows. Weights loaded as float4
// (VMEM-issue count /4: r10 theory says mlp was VMEM-issue bound).
__global__ __launch_bounds__(128, 3) void mlp_kernel(
  const float* __restrict__ feat, const float* __restrict__ xyz,
  const float* __restrict__ newxyz,
  const float* __restrict__ W0,const float* __restrict__ b0,
  const float* __restrict__ g0,const float* __restrict__ be0,
  const float* __restrict__ m0,const float* __restrict__ v0,
  const float* __restrict__ W1,const float* __restrict__ b1,
  const float* __restrict__ g1,const float* __restrict__ be1,
  const float* __restrict__ m1,const float* __restrict__ v1,
  const float* __restrict__ W2,const float* __restrict__ b2,
  const float* __restrict__ g2,const float* __restrict__ be2,
  const float* __restrict__ m2,const float* __restrict__ v2,
  float* __restrict__ out2)
{
  __shared__ float sX[128*67];
  const int tid=threadIdx.x;
  const int q=blockIdx.x*4+(tid>>5);
  const int k=tid&31;
  const int b=q>>10;
  const int pt=__float_as_int(out2[(size_t)q*128+k]);

  float* myx=sX+tid*67;
  {
    const float* nx=newxyz+(size_t)q*3;
    const float* pp=xyz+((size_t)b*NPTS+pt)*3;
    myx[0]=pp[0]-nx[0]; myx[1]=pp[1]-nx[1]; myx[2]=pp[2]-nx[2];
    const float4* fp=(const float4*)(feat+((size_t)b*NPTS+pt)*NCF);
    #pragma unroll
    for (int i=0;i<16;i++){
      float4 u=fp[i]; float* d=myx+3+i*4;
      d[0]=u.x; d[1]=u.y; d[2]=u.z; d[3]=u.w;
    }
  }
  float acc[64];
  // layer 1: 67 -> 64
  #pragma unroll
  for (int c=0;c<64;c++) acc[c]=b0[c];
  #pragma unroll 2
  for (int j=0;j<67;++j){
    float xj=myx[j];
    const float4* wr=(const float4*)(W0+j*64);
    #pragma unroll
    for (int c4=0;c4<16;c4++){
      float4 w=wr[c4];
      acc[c4*4+0]=fmaf(xj,w.x,acc[c4*4+0]);
      acc[c4*4+1]=fmaf(xj,w.y,acc[c4*4+1]);
      acc[c4*4+2]=fmaf(xj,w.z,acc[c4*4+2]);
      acc[c4*4+3]=fmaf(xj,w.w,acc[c4*4+3]);
    }
  }
  #pragma unroll
  for (int c=0;c<64;c++){
    float A=g0[c]*rsqrtf(v0[c]+1e-3f);
    myx[c]=fmaf(A,fmaxf(acc[c],0.0f),be0[c]-m0[c]*A);
  }
  // layer 2: 64 -> 64
  #pragma unroll
  for (int c=0;c<64;c++) acc[c]=b1[c];
  #pragma unroll 2
  for (int j=0;j<64;++j){
    float xj=myx[j];
    const float4* wr=(const float4*)(W1+j*64);
    #pragma unroll
    for (int c4=0;c4<16;c4++){
      float4 w=wr[c4];
      acc[c4*4+0]=fmaf(xj,w.x,acc[c4*4+0]);
      acc[c4*4+1]=fmaf(xj,w.y,acc[c4*4+1]);
      acc[c4*4+2]=fmaf(xj,w.z,acc[c4*4+2]);
      acc[c4*4+3]=fmaf(xj,w.w,acc[c4*4+3]);
    }
  }
  #pragma unroll
  for (int c=0;c<64;c++){
    float A=g1[c]*rsqrtf(v1[c]+1e-3f);
    myx[c]=fmaf(A,fmaxf(acc[c],0.0f),be1[c]-m1[c]*A);
  }
  // layer 3: 64 -> 128, two 64-col chunks (keeps VGPR low)
  #pragma unroll 1
  for (int ch=0;ch<2;++ch){
    const int co=ch*64;
    #pragma unroll
    for (int c=0;c<64;c++) acc[c]=b2[co+c];
    #pragma unroll 2
    for (int j=0;j<64;++j){
      float xj=myx[j];
      const float4* wr=(const float4*)(W2+j*128+co);
      #pragma unroll
      for (int c4=0;c4<16;c4++){
        float4 w=wr[c4];
        acc[c4*4+0]=fmaf(xj,w.x,acc[c4*4+0]);
        acc[c4*4+1]=fmaf(xj,w.y,acc[c4*4+1]);
        acc[c4*4+2]=fmaf(xj,w.z,acc[c4*4+2]);
        acc[c4*4+3]=fmaf(xj,w.w,acc[c4*4+3]);
      }
    }
    #pragma unroll
    for (int c=0;c<64;c++){
      float A=g2[co+c]*rsqrtf(v2[co+c]+1e-3f);
      float v=fmaf(A,fmaxf(acc[c],0.0f),be2[co+c]-m2[co+c]*A);
      v=fmaxf(v,__shfl_xor(v,1));
      v=fmaxf(v,__shfl_xor(v,2));
      v=fmaxf(v,__shfl_xor(v,4));
      v=fmaxf(v,__shfl_xor(v,8));
      v=fmaxf(v,__shfl_xor(v,16));
      acc[c]=v;
    }
    if (k==0){
      float4* op=(float4*)(out2+(size_t)q*128+co);
      #pragma unroll
      for (int c=0;c<64;c+=4)
        op[c/4]=make_float4(acc[c],acc[c+1],acc[c+2],acc[c+3]);
    }
  }
}

extern "C" void kernel_launch(void* const* d_in, const int* in_sizes, int n_in,
                              void* d_out, int out_size, void* d_ws, size_t ws_size,
                              hipStream_t stream)
{
  const float* xyz=(const float*)d_in[0];
  const float* feat=(const float*)d_in[1];
  float* out=(float*)d_out;
  float* out2=out+(size_t)NB*NS*3;     // pooled-feature region
  (void)d_ws; (void)ws_size;

  fps_kernel<<<NB,512,0,stream>>>(xyz,out);
  knn_kernel<<<NB*NS/16,256,0,stream>>>(xyz,out,out2);
  mlp_kernel<<<NB*NS/4,128,0,stream>>>(feat,xyz,out,
    (const float*)d_in[2],(const float*)d_in[3],
    (const float*)d_in[4],(const float*)d_in[5],
    (const float*)d_in[6],(const float*)d_in[7],
    (const float*)d_in[8],(const float*)d_in[9],
    (const float*)d_in[10],(const float*)d_in[11],
    (const float*)d_in[12],(const float*)d_in[13],
    (const float*)d_in[14],(const float*)d_in[15],
    (const float*)d_in[16],(const float*)d_in[17],
    (const float*)d_in[18],(const float*)d_in[19],
    out2);
}

// Round 11
// 1652.023 us; speedup vs baseline: 1.0259x; 1.0259x over previous
//
#include <hip/hip_runtime.h>

#define NB 16
#define NPTS 4096
#define NS 1024
#define NK 32
#define NCF 64

// All I/O is float32. Zero workspace bytes used. kNN parks its 32 indices
// (bit-cast to float) in the first 128B of each query's 512B output row;
// mlp_kernel reads them back and fully overwrites the row. Row ORDER of the
// 32 neighbors is irrelevant (max-pool) — only the index SET must be exact.
//
// REGISTER DISCIPLINE (r7-r11):
//  - __launch_bounds__ only CAPS VGPRs; arrays whose init source is LDS get
//    REMATERIALIZED from LDS regardless of budget (r9: (256,2) stayed VGPR 68).
//    Fix: source per-lane arrays from GLOBAL; keep the LDS copy written by
//    OTHER threads (cross-thread dataflow blocks the remat proof).
//  - knn lists need an explicit waves/EU bound for a >=128-VGPR budget.

#define F_INF __int_as_float(0x7f800000)

#define DPP_SHR1   0x111
#define DPP_SHR2   0x112
#define DPP_SHR4   0x114
#define DPP_SHR8   0x118
#define DPP_BCAST15 0x142
#define DPP_BCAST31 0x143

// one max step of a wave64 u64-key reduction via DPP (invalid lanes keep self)
#define DPP_MAX_STEP(cur, CTRL) do{ \
  int lo_=__builtin_amdgcn_update_dpp((int)(unsigned)(cur),(int)(unsigned)(cur),CTRL,0xF,0xF,false); \
  int hi_=__builtin_amdgcn_update_dpp((int)(unsigned)((cur)>>32),(int)(unsigned)((cur)>>32),CTRL,0xF,0xF,false); \
  unsigned long long nk_=(((unsigned long long)(unsigned)hi_)<<32)|(unsigned)lo_; \
  if (nk_>(cur)) (cur)=nk_; \
}while(0)

// ---------------- FPS: 1 block/batch, 256 thr (4 waves), DPP argmax ------
// key = (dist_bits<<32) | (4095-idx): u64 max == max dist, first index.
// Point arrays sourced from GLOBAL (strided p=r*256+tid) so they stay in
// registers; LDS holds a copy only for centroid lookup + output gather.
__global__ __launch_bounds__(256, 2) void fps_kernel(
  const float* __restrict__ xyz, float* __restrict__ out)
{
  __shared__ float sxyz[NPTS*3];
  __shared__ unsigned long long skey[2][4];
  __shared__ int sfps[NS];
  const int b = blockIdx.x, tid = threadIdx.x;
  const float* bp = xyz + (size_t)b*NPTS*3;

  { // stage xyz -> LDS (cross-thread layout: blocks remat of reg arrays)
    const float4* src=(const float4*)bp;
    float4* dst=(float4*)sxyz;
    for (int i=tid;i<NPTS*3/4;i+=256) dst[i]=src[i];
  }
  // 16 points per thread in registers, FROM GLOBAL, strided p=r*256+tid
  // (p ascends with r => strict > keeps the first/smallest global index)
  float px[16],py[16],pz[16],dist[16];
  #pragma unroll
  for (int r=0;r<16;r++){
    int p=r*256+tid;
    px[r]=bp[p*3]; py[r]=bp[p*3+1]; pz[r]=bp[p*3+2];
    dist[r]=1e10f;
  }
  __syncthreads();
  int far=0;
  for (int s=0;s<NS;++s){
    float cx=sxyz[far*3],cy=sxyz[far*3+1],cz=sxyz[far*3+2];
    float bv=-1.0f; int bslot=0;
    #pragma unroll
    for (int r=0;r<16;r++){
      float dx=__fsub_rn(px[r],cx);
      float dy=__fsub_rn(py[r],cy);
      float dz=__fsub_rn(pz[r],cz);
      float d2=__fadd_rn(__fadd_rn(__fmul_rn(dx,dx),__fmul_rn(dy,dy)),__fmul_rn(dz,dz));
      float nd=fminf(dist[r],d2);
      dist[r]=nd;
      if (nd>bv){bv=nd;bslot=r;}      // strict > keeps first index in lane
    }
    int bidx=bslot*256+tid;
    unsigned long long cur=(((unsigned long long)__float_as_uint(bv))<<32)
                           |(unsigned)(4095-bidx);
    DPP_MAX_STEP(cur,DPP_SHR1);
    DPP_MAX_STEP(cur,DPP_SHR2);
    DPP_MAX_STEP(cur,DPP_SHR4);
    DPP_MAX_STEP(cur,DPP_SHR8);
    DPP_MAX_STEP(cur,DPP_BCAST15);
    DPP_MAX_STEP(cur,DPP_BCAST31);
    const int par=s&1;
    if ((tid&63)==63) skey[par][tid>>6]=cur;
    __syncthreads();
    unsigned long long m=skey[par][0];
    #pragma unroll
    for (int w=1;w<4;w++){ unsigned long long o=skey[par][w]; if (o>m) m=o; }
    far=4095-(int)(m&0xFFFFFFFFu);
    if (tid==0) sfps[s]=far;
  }
  __syncthreads();
  for (int s=tid;s<NS;s+=256){
    int p=sfps[s];
    size_t o=((size_t)b*NS+s)*3;
    out[o]=sxyz[p*3]; out[o+1]=sxyz[p*3+1]; out[o+2]=sxyz[p*3+2];
  }
}

// ---------------- kNN: 256 thr (4 waves), 16 queries/block ----------------
// 16 lanes/query scan interleaved 256-pt partitions from GLOBAL (L1
// broadcast). Per-lane sorted top-32 via med3 insert. (256,3): 170-VGPR
// budget — testing whether (256,4)'s 128 cap still spilled the lists.
__global__ __launch_bounds__(256, 3) void knn_kernel(
  const float* __restrict__ xyz, const float* __restrict__ newxyz,
  float* __restrict__ out2)
{
  __shared__ unsigned long long sdump[64*33];  // 16.9 KB (one wave's lists)
  __shared__ unsigned long long sl1[16*33];    // 4.2 KB (level-1 outputs)
  const int tid=threadIdx.x;
  const int wave=tid>>6, lane=tid&63;
  const int qw=lane>>4;               // query-within-wave 0..3
  const int part=lane&15;             // partition 0..15
  const int gq=blockIdx.x*16+wave*4+qw;
  const int b=gq>>10;
  const float* base=xyz+(size_t)b*NPTS*3;

  float ax=newxyz[(size_t)gq*3],ay=newxyz[(size_t)gq*3+1],az=newxyz[(size_t)gq*3+2];
  float a2=__fadd_rn(__fadd_rn(__fmul_rn(ax,ax),__fmul_rn(ay,ay)),__fmul_rn(az,az));
  float kD[NK]; int kI[NK];
  #pragma unroll
  for (int p=0;p<NK;p++){kD[p]=F_INF;kI[p]=0x7FFFFFFF;}
  #pragma unroll 2
  for (int t=0;t<NPTS/16;++t){
    int n=(t<<4)|part;
    float bx=base[n*3],by=base[n*3+1],bz=base[n*3+2];
    float b2=__fadd_rn(__fadd_rn(__fmul_rn(bx,bx),__fmul_rn(by,by)),__fmul_rn(bz,bz));
    float ab=__fadd_rn(__fadd_rn(__fmul_rn(ax,bx),__fmul_rn(ay,by)),__fmul_rn(az,bz));
    float tt=__fadd_rn(__fsub_rn(a2,__fmul_rn(2.0f,ab)),b2);
    float d2=fmaxf(tt,0.0f);
    if (d2<kD[NK-1]){                  // strict <: in-lane (d2,idx) stability
      #pragma unroll
      for (int p=NK-1;p>0;--p){
        bool cm1=d2<kD[p-1];
        bool cp=d2<kD[p];
        kI[p]=cm1?kI[p-1]:(cp?n:kI[p]);
        kD[p]=__builtin_fminf(__builtin_fmaxf(kD[p-1],d2),kD[p]); // med3(sorted)
      }
      if (d2<kD[0]){kD[0]=d2;kI[0]=n;}
    }
  }
  // ---- 4-phase merge
  #pragma unroll 1
  for (int ph=0;ph<4;++ph){
    if (wave==ph){
      unsigned long long* row=sdump+(size_t)lane*33;
      #pragma unroll
      for (int p=0;p<NK;p++)
        row[p]=(((unsigned long long)__float_as_uint(kD[p]))<<32)|(unsigned)kI[p];
    }
    __syncthreads();
    if (tid<16){                        // level 1: query qq, group g
      int qq=tid>>2, g=tid&3;
      const unsigned long long* r0=sdump+(size_t)(qq*16+g*4+0)*33;
      const unsigned long long* r1=sdump+(size_t)(qq*16+g*4+1)*33;
      const unsigned long long* r2=sdump+(size_t)(qq*16+g*4+2)*33;
      const unsigned long long* r3=sdump+(size_t)(qq*16+g*4+3)*33;
      unsigned long long* o=sl1+(size_t)tid*33;
      int h0=0,h1=0,h2=0,h3=0;
      unsigned long long c0=r0[0],c1=r1[0],c2=r2[0],c3=r3[0];
      for (int i=0;i<NK;++i){
        bool s01=c1<c0; unsigned long long m01=s01?c1:c0;
        bool s23=c3<c2; unsigned long long m23=s23?c3:c2;
        bool sm=m23<m01; unsigned long long m=sm?m23:m01;
        o[i]=m;
        int w=sm?(s23?3:2):(s01?1:0);
        if (w==0){h0++; c0=(h0<NK)?r0[h0]:~0ull;}
        else if (w==1){h1++; c1=(h1<NK)?r1[h1]:~0ull;}
        else if (w==2){h2++; c2=(h2<NK)?r2[h2]:~0ull;}
        else {h3++; c3=(h3<NK)?r3[h3]:~0ull;}
      }
    }
    __syncthreads();
    if (tid<4){                         // level 2 -> output indices
      const unsigned long long* r0=sl1+(size_t)(tid*4+0)*33;
      const unsigned long long* r1=sl1+(size_t)(tid*4+1)*33;
      const unsigned long long* r2=sl1+(size_t)(tid*4+2)*33;
      const unsigned long long* r3=sl1+(size_t)(tid*4+3)*33;
      float* orow=out2+(size_t)(blockIdx.x*16+ph*4+tid)*128;
      int h0=0,h1=0,h2=0,h3=0;
      unsigned long long c0=r0[0],c1=r1[0],c2=r2[0],c3=r3[0];
      for (int i=0;i<NK;++i){
        bool s01=c1<c0; unsigned long long m01=s01?c1:c0;
        bool s23=c3<c2; unsigned long long m23=s23?c3:c2;
        bool sm=m23<m01; unsigned long long m=sm?m23:m01;
        orow[i]=__int_as_float((int)(unsigned)(m&0xFFFFFFFFu));
        int w=sm?(s23?3:2):(s01?1:0);
        if (w==0){h0++; c0=(h0<NK)?r0[h0]:~0ull;}
        else if (w==1){h1++; c1=(h1<NK)?r1[h1]:~0ull;}
        else if (w==2){h2++; c2=(h2<NK)?r2[h2]:~0ull;}
        else {h3++; c3=(h3<NK)?r3[h3]:~0ull;}
      }
    }
    __syncthreads();
  }
}

// ---------------- fused group + MLP(3) + maxpool --------------------------
// 128 threads = 4 queries x 32 neighbor rows. float4 weight loads.
__global__ __launch_bounds__(128, 3) void mlp_kernel(
  const float* __restrict__ feat, const float* __restrict__ xyz,
  const float* __restrict__ newxyz,
  const float* __restrict__ W0,const float* __restrict__ b0,
  const float* __restrict__ g0,const float* __restrict__ be0,
  const float* __restrict__ m0,const float* __restrict__ v0,
  const float* __restrict__ W1,const float* __restrict__ b1,
  const float* __restrict__ g1,const float* __restrict__ be1,
  const float* __restrict__ m1,const float* __restrict__ v1,
  const float* __restrict__ W2,const float* __restrict__ b2,
  const float* __restrict__ g2,const float* __restrict__ be2,
  const float* __restrict__ m2,const float* __restrict__ v2,
  float* __restrict__ out2)
{
  __shared__ float sX[128*67];
  const int tid=threadIdx.x;
  const int q=blockIdx.x*4+(tid>>5);
  const int k=tid&31;
  const int b=q>>10;
  const int pt=__float_as_int(out2[(size_t)q*128+k]);

  float* myx=sX+tid*67;
  {
    const float* nx=newxyz+(size_t)q*3;
    const float* pp=xyz+((size_t)b*NPTS+pt)*3;
    myx[0]=pp[0]-nx[0]; myx[1]=pp[1]-nx[1]; myx[2]=pp[2]-nx[2];
    const float4* fp=(const float4*)(feat+((size_t)b*NPTS+pt)*NCF);
    #pragma unroll
    for (int i=0;i<16;i++){
      float4 u=fp[i]; float* d=myx+3+i*4;
      d[0]=u.x; d[1]=u.y; d[2]=u.z; d[3]=u.w;
    }
  }
  float acc[64];
  // layer 1: 67 -> 64
  #pragma unroll
  for (int c=0;c<64;c++) acc[c]=b0[c];
  #pragma unroll 2
  for (int j=0;j<67;++j){
    float xj=myx[j];
    const float4* wr=(const float4*)(W0+j*64);
    #pragma unroll
    for (int c4=0;c4<16;c4++){
      float4 w=wr[c4];
      acc[c4*4+0]=fmaf(xj,w.x,acc[c4*4+0]);
      acc[c4*4+1]=fmaf(xj,w.y,acc[c4*4+1]);
      acc[c4*4+2]=fmaf(xj,w.z,acc[c4*4+2]);
      acc[c4*4+3]=fmaf(xj,w.w,acc[c4*4+3]);
    }
  }
  #pragma unroll
  for (int c=0;c<64;c++){
    float A=g0[c]*rsqrtf(v0[c]+1e-3f);
    myx[c]=fmaf(A,fmaxf(acc[c],0.0f),be0[c]-m0[c]*A);
  }
  // layer 2: 64 -> 64
  #pragma unroll
  for (int c=0;c<64;c++) acc[c]=b1[c];
  #pragma unroll 2
  for (int j=0;j<64;++j){
    float xj=myx[j];
    const float4* wr=(const float4*)(W1+j*64);
    #pragma unroll
    for (int c4=0;c4<16;c4++){
      float4 w=wr[c4];
      acc[c4*4+0]=fmaf(xj,w.x,acc[c4*4+0]);
      acc[c4*4+1]=fmaf(xj,w.y,acc[c4*4+1]);
      acc[c4*4+2]=fmaf(xj,w.z,acc[c4*4+2]);
      acc[c4*4+3]=fmaf(xj,w.w,acc[c4*4+3]);
    }
  }
  #pragma unroll
  for (int c=0;c<64;c++){
    float A=g1[c]*rsqrtf(v1[c]+1e-3f);
    myx[c]=fmaf(A,fmaxf(acc[c],0.0f),be1[c]-m1[c]*A);
  }
  // layer 3: 64 -> 128, two 64-col chunks (keeps VGPR low)
  #pragma unroll 1
  for (int ch=0;ch<2;++ch){
    const int co=ch*64;
    #pragma unroll
    for (int c=0;c<64;c++) acc[c]=b2[co+c];
    #pragma unroll 2
    for (int j=0;j<64;++j){
      float xj=myx[j];
      const float4* wr=(const float4*)(W2+j*128+co);
      #pragma unroll
      for (int c4=0;c4<16;c4++){
        float4 w=wr[c4];
        acc[c4*4+0]=fmaf(xj,w.x,acc[c4*4+0]);
        acc[c4*4+1]=fmaf(xj,w.y,acc[c4*4+1]);
        acc[c4*4+2]=fmaf(xj,w.z,acc[c4*4+2]);
        acc[c4*4+3]=fmaf(xj,w.w,acc[c4*4+3]);
      }
    }
    #pragma unroll
    for (int c=0;c<64;c++){
      float A=g2[co+c]*rsqrtf(v2[co+c]+1e-3f);
      float v=fmaf(A,fmaxf(acc[c],0.0f),be2[co+c]-m2[co+c]*A);
      v=fmaxf(v,__shfl_xor(v,1));
      v=fmaxf(v,__shfl_xor(v,2));
      v=fmaxf(v,__shfl_xor(v,4));
      v=fmaxf(v,__shfl_xor(v,8));
      v=fmaxf(v,__shfl_xor(v,16));
      acc[c]=v;
    }
    if (k==0){
      float4* op=(float4*)(out2+(size_t)q*128+co);
      #pragma unroll
      for (int c=0;c<64;c+=4)
        op[c/4]=make_float4(acc[c],acc[c+1],acc[c+2],acc[c+3]);
    }
  }
}

extern "C" void kernel_launch(void* const* d_in, const int* in_sizes, int n_in,
                              void* d_out, int out_size, void* d_ws, size_t ws_size,
                              hipStream_t stream)
{
  const float* xyz=(const float*)d_in[0];
  const float* feat=(const float*)d_in[1];
  float* out=(float*)d_out;
  float* out2=out+(size_t)NB*NS*3;     // pooled-feature region
  (void)d_ws; (void)ws_size;

  fps_kernel<<<NB,256,0,stream>>>(xyz,out);
  knn_kernel<<<NB*NS/16,256,0,stream>>>(xyz,out,out2);
  mlp_kernel<<<NB*NS/4,128,0,stream>>>(feat,xyz,out,
    (const float*)d_in[2],(const float*)d_in[3],
    (const float*)d_in[4],(const float*)d_in[5],
    (const float*)d_in[6],(const float*)d_in[7],
    (const float*)d_in[8],(const float*)d_in[9],
    (const float*)d_in[10],(const float*)d_in[11],
    (const float*)d_in[12],(const float*)d_in[13],
    (const float*)d_in[14],(const float*)d_in[15],
    (const float*)d_in[16],(const float*)d_in[17],
    (const float*)d_in[18],(const float*)d_in[19],
    out2);
}